// Round 8
// baseline (288.167 us; speedup 1.0000x reference)
//
#include <hip/hip_runtime.h>

// Masked attention B=8, NQ=1024, S=2048, D=512, fp32 in/out.
// prep: K -> Kf fp16; V -> Vt fp16 [b][d][s]; mask -> bit-packed Mp (2MB).
// attn_flash r16: D-SPLIT WORKGROUPS -> 12 waves/CU.
//   Occupancy was VGPR-capped all along (unified file: oacc 128 AGPR + ~128
//   arch = ~256/wave -> 8 waves/CU in r12/r14 regardless of LDS). Fix:
//   - WG owns d-half [dh*256, +256) for 64 q-rows (4 waves x 16): oacc
//     halves to 64 AGPR. __launch_bounds__(256,3) -> 3 WGs x 4 = 12 waves/CU.
//   - sP DELETED: P A-frag gathered in-register via 8 __shfl + selects
//     (target quad tq needs k=tq*8..+7 = pb[tq>=2] of lanes
//     l16+32*(tq&1)+{0,16}). LDS = sK 33.3 + sV 16.4 = 49.7KB -> 3 WGs fit.
//   - QK redundant per d-half pair (+33% MFMA at 16% util - cheap); K staged
//     x2, Q read x2 (~+20MB L2, overlapped).
//   - r14's 2-surgical-drain single-buffer schedule (drain BEFORE barrier:
//     vmcnt is per-wave; barrier makes all waves' retirement global):
//       B1: vmcnt(0)[retires V(i)+mask]; s_barrier; issue K(i+1)  [flight=PV]
//       B2: vmcnt(0)[retires K(i+1)];    s_barrier; issue V(i+1)  [flight=QK+sm]
//   - QK as 2 MFMA chains (-8 arch regs for the forced reg cap).
//   - split=2, grid = 8b x 16qt x 2sh x 2dh = 512 WGs.
// combine: merge the 2 S-parts (fp16 Opart).

#define Bz 8
#define NQz 1024
#define Sz 2048
#define Dz 512
#define QTT 64    // q rows per WG (4 waves x 16)
#define TS 32
#define KP 520    // sK row pitch (f16); 1040B rows (16B-aligned rows)

typedef _Float16 f16x8 __attribute__((ext_vector_type(8)));
typedef float f32x4 __attribute__((ext_vector_type(4)));
typedef unsigned short ushort_t;

#define AS1(p) ((const __attribute__((address_space(1))) unsigned int*)(p))
#define AS3(p) ((__attribute__((address_space(3))) unsigned int*)(p))
#define DRAIN_ALL() __builtin_amdgcn_s_waitcnt(0)
// surgical drain + raw barrier (loads issued AFTER this stay untouched)
#define DRAIN_BAR()                                         \
  do {                                                      \
    asm volatile("s_waitcnt vmcnt(0)" ::: "memory");        \
    __builtin_amdgcn_s_barrier();                           \
    asm volatile("" ::: "memory");                          \
  } while (0)

__device__ __forceinline__ ushort_t f2h(float x) {
  _Float16 h = (_Float16)x;  // RNE
  return __builtin_bit_cast(ushort_t, h);
}
__device__ __forceinline__ float h2f(ushort_t u) {
  return (float)__builtin_bit_cast(_Float16, u);
}

// ---- prep: K -> fp16 | V -> Vt fp16 transposed | mask -> bitpack ----
__global__ __launch_bounds__(256)
void prep(const float* __restrict__ K, const float* __restrict__ V,
          const int* __restrict__ Mi, ushort_t* __restrict__ Kf,
          ushort_t* __restrict__ Vt, unsigned* __restrict__ Mp) {
  __shared__ ushort_t sT[64][41];
  const int t = threadIdx.x;
  int bx = blockIdx.x;
  if (bx < 2048) {  // K fp32 -> fp16: 16 elems/thread, 4 independent streams
    const size_t base = (size_t)bx * 4096 + t * 4;
#pragma unroll
    for (int i = 0; i < 4; ++i) {
      size_t e = base + i * 1024;
      float4 v = *(const float4*)(K + e);
      uint2 w;
      w.x = (unsigned)f2h(v.x) | ((unsigned)f2h(v.y) << 16);
      w.y = (unsigned)f2h(v.z) | ((unsigned)f2h(v.w) << 16);
      *(uint2*)(Kf + e) = w;
    }
    return;
  }
  bx -= 2048;
  if (bx < 4096) {  // V transpose, 64s x 32d tiles, 128B write segments
    const int b = bx >> 9;
    const int rest = bx & 511;
    const int st = rest >> 4;
    const int dt = rest & 15;
    const int s0 = st * 64, d0 = dt * 32;
    const float* Vb = V + ((size_t)b * Sz + s0) * Dz + d0;
#pragma unroll
    for (int i = 0; i < 2; ++i) {
      int idx = t + 256 * i;
      int s = idx >> 3;
      int dc = (idx & 7) * 4;
      float4 v = *(const float4*)(Vb + (size_t)s * Dz + dc);
      uint2 w;
      w.x = (unsigned)f2h(v.x) | ((unsigned)f2h(v.y) << 16);
      w.y = (unsigned)f2h(v.z) | ((unsigned)f2h(v.w) << 16);
      *(uint2*)(&sT[s][dc]) = w;
    }
    __syncthreads();
    ushort_t* VtB = Vt + ((size_t)b * Dz + d0) * Sz + s0;
    int d = t >> 3, c = t & 7;
    uint4 u;
    ushort_t* tp = (ushort_t*)&u;
#pragma unroll
    for (int j = 0; j < 8; ++j) tp[j] = sT[c * 8 + j][d];
    *(uint4*)(VtB + (size_t)d * Sz + c * 8) = u;
    return;
  }
  bx -= 4096;  // mask bitpack: 4096 ints/block over 4 iterations
  const int lane = t & 63;
#pragma unroll
  for (int i = 0; i < 4; ++i) {
    const size_t base = (size_t)bx * 4096 + i * 1024 + t * 4;
    const int4 mv = *(const int4*)(Mi + base);
    unsigned nib = (mv.x ? 1u : 0u) | (mv.y ? 2u : 0u) |
                   (mv.z ? 4u : 0u) | (mv.w ? 8u : 0u);
    unsigned v = nib << ((lane & 7) * 4);
    v |= __shfl_xor(v, 1);
    v |= __shfl_xor(v, 2);
    v |= __shfl_xor(v, 4);
    if ((lane & 7) == 0) Mp[bx * 128 + i * 32 + (t >> 3)] = v;
  }
}

// ---------------- attention ----------------
template <int SPLIT>
__global__ __launch_bounds__(256, 3)
void attn_flash(const float* __restrict__ Q, const unsigned* __restrict__ Mp,
                const ushort_t* __restrict__ Kf, const ushort_t* __restrict__ Vt,
                ushort_t* __restrict__ Opart, float* __restrict__ Mpart,
                float* __restrict__ Lpart) {
  __shared__ ushort_t sK[TS][KP];     // 33.28 KB
  __shared__ ushort_t sV[256][TS];    // 16.38 KB (this WG's d-half; swizzled)

  const int tid  = threadIdx.x;
  const int wave = tid >> 6;          // 0..3 = q-group
  const int lane = tid & 63;
  const int l16  = lane & 15;
  const int quad = lane >> 4;

  const int bxr = blockIdx.x;
  const int b   = bxr & 7;            // XCD swizzle: b == XCD
  const int rest = bxr >> 3;          // qt | sh | dh
  const int dh  = rest & 1;
  const int r2  = rest >> 1;
  const int sh  = r2 % SPLIT;
  const int qt  = r2 / SPLIT;
  const int q0  = qt * QTT;
  const int d0  = dh * 256;
  const int SLEN = Sz / SPLIT;
  const int NTt  = SLEN / TS;
  const int sbeg = sh * SLEN;
  const int qw   = q0 + wave * 16;    // this wave's q base

  const float*    Qb  = Q  + ((size_t)b * NQz + qw) * Dz;
  const ushort_t* KfB = Kf + (size_t)b * Sz * Dz;
  const ushort_t* VtB = Vt + (size_t)b * Dz * Sz;
  const unsigned* MpB = Mp + ((size_t)b * NQz + qw) * (Sz / 32);

  // sV swizzle: physical 16B slot = logical_quad ^ ((row>>1)&3) (r12-proven).
  const int vql  = (lane & 3) ^ ((lane >> 3) & 3);   // DMA source slot
  const int vcol = (quad ^ ((l16 >> 1) & 3)) * 8;    // read slot (f16 elems)

  auto issue_k = [&](int s0n) {                      // 8 VMEM instr / wave
#pragma unroll
    for (int j = 0; j < 8; ++j) {
      int row = wave * 8 + j;
      const ushort_t* gp = KfB + (size_t)(s0n + row) * Dz + lane * 8;
      __builtin_amdgcn_global_load_lds(AS1(gp), AS3(&sK[row][0]), 16, 0, 0);
    }
  };
  auto issue_v = [&](int s0n) {                      // 4 VMEM instr / wave
#pragma unroll
    for (int j = 0; j < 4; ++j) {
      int dbase = wave * 64 + j * 16;                // local d row
      int d = d0 + dbase + (lane >> 2);
      const ushort_t* gp = VtB + (size_t)d * Sz + s0n + vql * 8;
      __builtin_amdgcn_global_load_lds(AS1(gp), AS3(&sV[dbase][0]), 16, 0, 0);
    }
  };
  auto load_mask = [&](int s0n) -> unsigned {
    return MpB[(size_t)l16 * (Sz / 32) + (s0n >> 5)];
  };

  // ---- prologue: DMA(0), mask(0), Q frags; full drain + real barrier ----
  issue_k(sbeg);
  issue_v(sbeg);
  unsigned msk_cur = load_mask(sbeg);

  f16x8 qa[16];  // Q row qw+l16, fp16; B-operand of swapped QK (64 VGPR)
  {
    const float* qrow = Qb + (size_t)l16 * Dz;
#pragma unroll
    for (int kk = 0; kk < 16; ++kk) {
      const float4 a = *(const float4*)(qrow + kk * 32 + quad * 8);
      const float4 c = *(const float4*)(qrow + kk * 32 + quad * 8 + 4);
      f16x8 h;
      h[0] = (_Float16)a.x; h[1] = (_Float16)a.y;
      h[2] = (_Float16)a.z; h[3] = (_Float16)a.w;
      h[4] = (_Float16)c.x; h[5] = (_Float16)c.y;
      h[6] = (_Float16)c.z; h[7] = (_Float16)c.w;
      qa[kk] = h;
    }
  }
  DRAIN_ALL();
  __syncthreads();

  float m_ln = -1e30f, l_ln = 0.0f;  // running stats for q = qw + l16
  f32x4 oacc[16];                     // 64 AGPR (d-half only)
#pragma unroll
  for (int nt = 0; nt < 16; ++nt) oacc[nt] = (f32x4){0.f, 0.f, 0.f, 0.f};

  for (int i = 0; i < NTt; ++i) {
    // ---- QK: S^T = K·Q^T, 2 chains (rows l16 and 16+l16) ----
    f32x4 s0v = (f32x4){0.f, 0.f, 0.f, 0.f};
    f32x4 s1v = (f32x4){0.f, 0.f, 0.f, 0.f};
    {
      const ushort_t* kh0 = &sK[l16][quad * 8];
      const ushort_t* kh1 = &sK[16 + l16][quad * 8];
      __builtin_amdgcn_s_setprio(1);
#pragma unroll
      for (int kk = 0; kk < 16; ++kk) {
        f16x8 k0 = *(const f16x8*)(kh0 + kk * 32);
        f16x8 k1 = *(const f16x8*)(kh1 + kk * 32);
        s0v = __builtin_amdgcn_mfma_f32_16x16x32_f16(k0, qa[kk], s0v, 0, 0, 0);
        s1v = __builtin_amdgcn_mfma_f32_16x16x32_f16(k1, qa[kk], s1v, 0, 0, 0);
      }
      __builtin_amdgcn_s_setprio(0);
    }

    // ---- intra-wave masked softmax; lane: q=l16, s=quad*4+r (+16) ----
    const unsigned mb = msk_cur;
    float se0[4], se1[4];
#pragma unroll
    for (int r = 0; r < 4; ++r) {
      se0[r] = ((mb >> (quad * 4 + r)) & 1u)      ? s0v[r] : -1e30f;
      se1[r] = ((mb >> (16 + quad * 4 + r)) & 1u) ? s1v[r] : -1e30f;
    }
    float rmax = fmaxf(fmaxf(fmaxf(se0[0], se0[1]), fmaxf(se0[2], se0[3])),
                       fmaxf(fmaxf(se1[0], se1[1]), fmaxf(se1[2], se1[3])));
    rmax = fmaxf(rmax, __shfl_xor(rmax, 16));
    rmax = fmaxf(rmax, __shfl_xor(rmax, 32));

    ushort_t pb0[4], pb1[4];
    float rsum = 0.f;
#pragma unroll
    for (int r = 0; r < 4; ++r) {
      float p0 = ((mb >> (quad * 4 + r)) & 1u)      ? __expf(se0[r] - rmax) : 0.f;
      float p1 = ((mb >> (16 + quad * 4 + r)) & 1u) ? __expf(se1[r] - rmax) : 0.f;
      pb0[r] = f2h(p0); pb1[r] = f2h(p1);
      rsum += h2f(pb0[r]) + h2f(pb1[r]);
    }
    rsum += __shfl_xor(rsum, 16);
    rsum += __shfl_xor(rsum, 32);

    float m_new = fmaxf(m_ln, rmax);
    float scl   = __expf(rmax - m_new);
    float al_ln = __expf(m_ln - m_new);
    bool  grw   = m_new > m_ln;
    l_ln = al_ln * l_ln + scl * rsum;
    m_ln = m_new;

    // ---- P A-frag via register shuffles (sP deleted) ----
    // lane holds s=quad*4+r (pb0) and 16+quad*4+r (pb1) for its q-row l16.
    // Target (l16,tq) needs k=tq*8..+7 = pb[tq>=2] of lanes
    // l16 + 32*(tq&1) + {0,16}.
    f16x8 pa;
    {
      unsigned u0a = (unsigned)pb0[0] | ((unsigned)pb0[1] << 16);
      unsigned u0b = (unsigned)pb0[2] | ((unsigned)pb0[3] << 16);
      unsigned u1a = (unsigned)pb1[0] | ((unsigned)pb1[1] << 16);
      unsigned u1b = (unsigned)pb1[2] | ((unsigned)pb1[3] << 16);
      const int sA = l16 + ((quad & 1) ? 32 : 0);
      const int sB = sA + 16;
      unsigned lo0 = __shfl((int)u0a, sA), lo1 = __shfl((int)u0b, sA);
      unsigned lo2 = __shfl((int)u0a, sB), lo3 = __shfl((int)u0b, sB);
      unsigned hi0 = __shfl((int)u1a, sA), hi1 = __shfl((int)u1b, sA);
      unsigned hi2 = __shfl((int)u1a, sB), hi3 = __shfl((int)u1b, sB);
      const bool hi = quad >= 2;
      uint4 w;
      w.x = hi ? hi0 : lo0;  w.y = hi ? hi1 : lo1;
      w.z = hi ? hi2 : lo2;  w.w = hi ? hi3 : lo3;
      f16x8 praw = __builtin_bit_cast(f16x8, w);
      _Float16 sh16 = (_Float16)scl;
#pragma unroll
      for (int j = 0; j < 8; ++j) pa[j] = praw[j] * sh16;  // v_pk_mul_f16
    }

    // ---- B1: all QK(i) reads done; V(i)+mask retired wave-wide ----
    DRAIN_BAR();
    unsigned msk_nxt = 0;
    if (i + 1 < NTt) {
      msk_nxt = load_mask(sbeg + (i + 1) * TS);
      issue_k(sbeg + (i + 1) * TS);   // flight = PV(i)
    }

    if (__any((int)grw)) {  // EXACT skip: all alphas == 1 when no max grew
      float alr[4];
#pragma unroll
      for (int r = 0; r < 4; ++r) alr[r] = __shfl(al_ln, quad * 4 + r);
#pragma unroll
      for (int nt = 0; nt < 16; ++nt)
#pragma unroll
        for (int r = 0; r < 4; ++r) oacc[nt][r] *= alr[r];
    }

    // ---- PV: 16 MFMAs over this WG's 256-d half, swizzled sV reads ----
    {
      const ushort_t* vb_ = &sV[0][0] + (size_t)l16 * TS + vcol;
      __builtin_amdgcn_s_setprio(1);
#pragma unroll
      for (int nt = 0; nt < 16; ++nt) {
        f16x8 vb = *(const f16x8*)(vb_ + nt * 512);
        oacc[nt] = __builtin_amdgcn_mfma_f32_16x16x32_f16(pa, vb, oacc[nt], 0, 0, 0);
      }
      __builtin_amdgcn_s_setprio(0);
    }

    // ---- B2: all PV(i) reads done; K(i+1)+mask retired wave-wide ----
    DRAIN_BAR();
    if (i + 1 < NTt) issue_v(sbeg + (i + 1) * TS);  // flight = QK(i+1)+softmax

    msk_cur = msk_nxt;
  }

  // ---- epilogue: all state register-resident ----
  const size_t rbase = (size_t)(b * SPLIT + sh) * NQz + q0 + wave * 16;
#pragma unroll
  for (int nt = 0; nt < 16; ++nt) {
#pragma unroll
    for (int r = 0; r < 4; ++r) {
      Opart[(rbase + quad * 4 + r) * Dz + d0 + nt * 16 + l16] = f2h(oacc[nt][r]);
    }
  }
  if (dh == 0 && quad == 0) {   // partner d-half WG has identical stats
    Mpart[rbase + l16] = m_ln;
    Lpart[rbase + l16] = l_ln;
  }
}

// ---------------- combine the SPLIT S-parts (fp16 Opart) ----------------
template <int SPLIT>
__global__ __launch_bounds__(256)
void combine(const ushort_t* __restrict__ Opart, const float* __restrict__ Mpart,
             const float* __restrict__ Lpart, float* __restrict__ Out) {
  int gid = blockIdx.x * 256 + threadIdx.x;
  int row = gid >> 7;
  int b   = row >> 10;
  int q   = row & 1023;
  int c   = (gid & 127) * 4;
  float mv[SPLIT], lv[SPLIT];
  float m = -1e30f;
#pragma unroll
  for (int p = 0; p < SPLIT; ++p) {
    size_t ip = (size_t)(b * SPLIT + p) * NQz + q;
    mv[p] = Mpart[ip];
    lv[p] = Lpart[ip];
    m = fmaxf(m, mv[p]);
  }
  float w[SPLIT], denom = 0.f;
#pragma unroll
  for (int p = 0; p < SPLIT; ++p) {
    w[p] = __expf(mv[p] - m);
    denom += w[p] * lv[p];
  }
  float inv = 1.0f / denom;
  float4 o = {0.f, 0.f, 0.f, 0.f};
#pragma unroll
  for (int p = 0; p < SPLIT; ++p) {
    size_t ip = (size_t)(b * SPLIT + p) * NQz + q;
    const ushort_t* op = Opart + ip * Dz + c;
    uint2 raw = *(const uint2*)op;
    o.x += w[p] * h2f((ushort_t)(raw.x & 0xffff));
    o.y += w[p] * h2f((ushort_t)(raw.x >> 16));
    o.z += w[p] * h2f((ushort_t)(raw.y & 0xffff));
    o.w += w[p] * h2f((ushort_t)(raw.y >> 16));
  }
  o.x *= inv; o.y *= inv; o.z *= inv; o.w *= inv;
  *(float4*)(Out + ((size_t)b * NQz + q) * Dz + c) = o;
}

extern "C" void kernel_launch(void* const* d_in, const int* in_sizes, int n_in,
                              void* d_out, int out_size, void* d_ws, size_t ws_size,
                              hipStream_t stream) {
  const float* Q = (const float*)d_in[0];
  const float* K = (const float*)d_in[1];
  const float* V = (const float*)d_in[2];
  const int*   M = (const int*)d_in[3];
  float* O = (float*)d_out;

  const size_t NKV   = (size_t)Bz * Sz * Dz;        // f16 elems per tensor
  const size_t maskW = (size_t)Bz * NQz * (Sz / 32);

  // Layout: Kf | Vt | Mp | Opart(fp16) | Mpart | Lpart  (split=2: ~53MB)
  ushort_t* Kf = (ushort_t*)d_ws;
  ushort_t* Vt = Kf + NKV;
  unsigned* Mp = (unsigned*)(Vt + NKV);
  ushort_t* Opart = (ushort_t*)(Mp + maskW);

  constexpr int S = 2;
  float* Mpart = (float*)(Opart + (size_t)Bz * S * NQz * Dz);
  float* Lpart = Mpart + (size_t)Bz * S * NQz;

  // 2048 K-convert + 4096 V-transpose + 4096 mask-pack blocks
  prep<<<dim3(10240), dim3(256), 0, stream>>>(K, V, M, Kf, Vt, Mp);
  // grid = 8b x 16qt x Ssh x 2dh = 512 WGs
  attn_flash<S><<<dim3(8 * (NQz / QTT) * S * 2), dim3(256), 0, stream>>>(
      Q, Mp, Kf, Vt, Opart, Mpart, Lpart);
  combine<S><<<dim3(4096), dim3(256), 0, stream>>>(Opart, Mpart, Lpart, O);
}

// Round 9
// 247.563 us; speedup vs baseline: 1.1640x; 1.1640x over previous
//
#include <hip/hip_runtime.h>

// Masked attention B=8, NQ=1024, S=2048, D=512, fp32 in/out.
// prep: K -> Kf fp16; V -> Vt fp16 [b][d][s]; mask -> bit-packed Mp (2MB).
// attn_flash r17: LDS-traffic cut (the measured floor: ~41us of ds_read at
//   85B/cy dominated r12's 83.5us; time scales with per-wave work, r16 data).
//   Geometry = r12 (256 WGs x 8 waves, QTT=128, split=4) but PV re-partitioned:
//   - wave w: QK for q-rows w*16..+15 (r12 verbatim), PV for ALL 128q x
//     d-slice [w*64,+64).
//   - V NEVER in LDS: per tile the wave's V-slice (32s x 64d = 16 VGPRs) is
//     loaded from Vt in XCD-local L2 with the same per-lane f16x8 pattern.
//     Removes 256KB/WG/tile of V LDS re-reads + the V DMA.
//   - P through sP once, PRE-SCALED to exp(s - m_new) (producer side), so
//     consumers read 1KB A-frag per q-block reused over 4 d-tiles
//     (8 b128/wave/tile). Per-row oacc alphas via sAl[128] f32 (broadcast
//     reads). Always-rescale (no cross-wave skip flag).
//   - ONE barrier/tile, counted drains (no vmcnt(0) in loop): vmcnt(5)
//     retires K(i+1) keeping V(i)+mask(i+1) in flight; lgkmcnt(0)+s_barrier
//     publishes sP/sAl; K(i+2) DMA issued post-barrier (flight ~1 tile).
//   - LDS 77.3KB; ~330KB LDS traffic/WG/tile vs r12's ~530KB.
// combine: merge the SPLIT S-parts (fp16 Opart).

#define Bz 8
#define NQz 1024
#define Sz 2048
#define Dz 512
#define QTT 128   // q rows per WG (8 waves x 16)
#define TS 32
#define KP 520    // sK row pitch (f16); uniform-bank on QK reads
#define PP 40     // sP row pitch (f16); uniform-bank on A-frag reads

typedef _Float16 f16x8 __attribute__((ext_vector_type(8)));
typedef float f32x4 __attribute__((ext_vector_type(4)));
typedef unsigned short ushort_t;

#define AS1(p) ((const __attribute__((address_space(1))) unsigned int*)(p))
#define AS3(p) ((__attribute__((address_space(3))) unsigned int*)(p))
#define DRAIN_ALL() __builtin_amdgcn_s_waitcnt(0)

__device__ __forceinline__ ushort_t f2h(float x) {
  _Float16 h = (_Float16)x;  // RNE
  return __builtin_bit_cast(ushort_t, h);
}
__device__ __forceinline__ float h2f(ushort_t u) {
  return (float)__builtin_bit_cast(_Float16, u);
}

// ---- prep: K -> fp16 | V -> Vt fp16 transposed | mask -> bitpack ----
__global__ __launch_bounds__(256)
void prep(const float* __restrict__ K, const float* __restrict__ V,
          const int* __restrict__ Mi, ushort_t* __restrict__ Kf,
          ushort_t* __restrict__ Vt, unsigned* __restrict__ Mp) {
  __shared__ ushort_t sT[64][41];
  const int t = threadIdx.x;
  int bx = blockIdx.x;
  if (bx < 2048) {  // K fp32 -> fp16: 16 elems/thread, 4 independent streams
    const size_t base = (size_t)bx * 4096 + t * 4;
#pragma unroll
    for (int i = 0; i < 4; ++i) {
      size_t e = base + i * 1024;
      float4 v = *(const float4*)(K + e);
      uint2 w;
      w.x = (unsigned)f2h(v.x) | ((unsigned)f2h(v.y) << 16);
      w.y = (unsigned)f2h(v.z) | ((unsigned)f2h(v.w) << 16);
      *(uint2*)(Kf + e) = w;
    }
    return;
  }
  bx -= 2048;
  if (bx < 4096) {  // V transpose, 64s x 32d tiles, 128B write segments
    const int b = bx >> 9;
    const int rest = bx & 511;
    const int st = rest >> 4;
    const int dt = rest & 15;
    const int s0 = st * 64, d0 = dt * 32;
    const float* Vb = V + ((size_t)b * Sz + s0) * Dz + d0;
#pragma unroll
    for (int i = 0; i < 2; ++i) {
      int idx = t + 256 * i;
      int s = idx >> 3;
      int dc = (idx & 7) * 4;
      float4 v = *(const float4*)(Vb + (size_t)s * Dz + dc);
      uint2 w;
      w.x = (unsigned)f2h(v.x) | ((unsigned)f2h(v.y) << 16);
      w.y = (unsigned)f2h(v.z) | ((unsigned)f2h(v.w) << 16);
      *(uint2*)(&sT[s][dc]) = w;
    }
    __syncthreads();
    ushort_t* VtB = Vt + ((size_t)b * Dz + d0) * Sz + s0;
    int d = t >> 3, c = t & 7;
    uint4 u;
    ushort_t* tp = (ushort_t*)&u;
#pragma unroll
    for (int j = 0; j < 8; ++j) tp[j] = sT[c * 8 + j][d];
    *(uint4*)(VtB + (size_t)d * Sz + c * 8) = u;
    return;
  }
  bx -= 4096;  // mask bitpack: 4096 ints/block over 4 iterations
  const int lane = t & 63;
#pragma unroll
  for (int i = 0; i < 4; ++i) {
    const size_t base = (size_t)bx * 4096 + i * 1024 + t * 4;
    const int4 mv = *(const int4*)(Mi + base);
    unsigned nib = (mv.x ? 1u : 0u) | (mv.y ? 2u : 0u) |
                   (mv.z ? 4u : 0u) | (mv.w ? 8u : 0u);
    unsigned v = nib << ((lane & 7) * 4);
    v |= __shfl_xor(v, 1);
    v |= __shfl_xor(v, 2);
    v |= __shfl_xor(v, 4);
    if ((lane & 7) == 0) Mp[bx * 128 + i * 32 + (t >> 3)] = v;
  }
}

// ---------------- attention ----------------
template <int SPLIT>
__global__ __launch_bounds__(512, 2)
void attn_flash(const float* __restrict__ Q, const unsigned* __restrict__ Mp,
                const ushort_t* __restrict__ Kf, const ushort_t* __restrict__ Vt,
                ushort_t* __restrict__ Opart, float* __restrict__ Mpart,
                float* __restrict__ Lpart) {
  __shared__ ushort_t sK[2][TS][KP];   // 66.56 KB (double-buffered)
  __shared__ ushort_t sP[QTT][PP];     // 10.24 KB (128q x 32s, pre-scaled)
  __shared__ float    sAl[QTT];        // 0.5 KB (per-row oacc alphas)

  const int tid  = threadIdx.x;
  const int wave = tid >> 6;           // 0..7: q-block (QK) / d-slice (PV)
  const int lane = tid & 63;
  const int l16  = lane & 15;
  const int quad = lane >> 4;

  const int bxr = blockIdx.x;
  const int b   = bxr & 7;             // XCD swizzle: b == XCD
  const int rest = bxr >> 3;
  const int qt  = rest / SPLIT;
  const int sh  = rest % SPLIT;
  const int q0  = qt * QTT;
  const int SLEN = Sz / SPLIT;
  const int NTt  = SLEN / TS;
  const int sbeg = sh * SLEN;
  const int qw   = q0 + wave * 16;     // this wave's QK q base

  const float*    Qb  = Q  + ((size_t)b * NQz + qw) * Dz;
  const ushort_t* KfB = Kf + (size_t)b * Sz * Dz;
  const ushort_t* VtB = Vt + (size_t)b * Dz * Sz;
  const unsigned* MpB = Mp + ((size_t)b * NQz + qw) * (Sz / 32);

  auto issue_k = [&](int s0n, int bsel) {   // 4 VMEM instr / wave (8 waves)
#pragma unroll
    for (int j = 0; j < 4; ++j) {
      int row = wave * 4 + j;
      const ushort_t* gp = KfB + (size_t)(s0n + row) * Dz + lane * 8;
      __builtin_amdgcn_global_load_lds(AS1(gp), AS3(&sK[bsel][row][0]), 16, 0, 0);
    }
  };
  auto load_mask = [&](int s0n) -> unsigned {
    return MpB[(size_t)l16 * (Sz / 32) + (s0n >> 5)];
  };
  // V B-frag pointer: wave's d-slice [wave*64,+64), lane n=l16 -> d, k=quad*8+j
  const ushort_t* VtW = VtB + (size_t)(wave * 64 + l16) * Sz;

  // ---- prologue: K(0),K(1) DMA; mask(0); Q frags; full drain ----
  issue_k(sbeg, 0);
  if (NTt > 1) issue_k(sbeg + TS, 1);
  unsigned msk_cur = load_mask(sbeg);

  f16x8 qa[16];  // Q row qw+l16, fp16; B-operand of swapped QK (r12 verbatim)
  {
    const float* qrow = Qb + (size_t)l16 * Dz;
#pragma unroll
    for (int kk = 0; kk < 16; ++kk) {
      const float4 a = *(const float4*)(qrow + kk * 32 + quad * 8);
      const float4 c = *(const float4*)(qrow + kk * 32 + quad * 8 + 4);
      f16x8 h;
      h[0] = (_Float16)a.x; h[1] = (_Float16)a.y;
      h[2] = (_Float16)a.z; h[3] = (_Float16)a.w;
      h[4] = (_Float16)c.x; h[5] = (_Float16)c.y;
      h[6] = (_Float16)c.z; h[7] = (_Float16)c.w;
      qa[kk] = h;
    }
  }
  DRAIN_ALL();
  __syncthreads();

  float m_ln = -1e30f, l_ln = 0.0f;  // running stats for q = qw + l16
  f32x4 oacc[32];                    // all 128q x this wave's 64d
#pragma unroll
  for (int nt = 0; nt < 32; ++nt) oacc[nt] = (f32x4){0.f, 0.f, 0.f, 0.f};

  for (int i = 0; i < NTt; ++i) {
    const int buf = i & 1;
    const int s0  = sbeg + i * TS;

    // ---- step 0: V(i) slice -> regs (L2); mask(i+1) ----
    f16x8 vb[4];
#pragma unroll
    for (int dt = 0; dt < 4; ++dt)
      vb[dt] = *(const f16x8*)(VtW + (size_t)(dt * 16) * Sz + s0 + quad * 8);
    unsigned msk_nxt = (i + 1 < NTt) ? load_mask(s0 + TS) : 0u;

    // ---- step 1: QK(i) from sK[buf] (r12 verbatim, 4 chains) ----
    f32x4 a00 = (f32x4){0.f,0.f,0.f,0.f}, a01 = (f32x4){0.f,0.f,0.f,0.f};
    f32x4 a10 = (f32x4){0.f,0.f,0.f,0.f}, a11 = (f32x4){0.f,0.f,0.f,0.f};
    {
      const ushort_t* kh0 = &sK[buf][l16][quad * 8];
      const ushort_t* kh1 = &sK[buf][16 + l16][quad * 8];
#pragma unroll
      for (int kk = 0; kk < 16; kk += 2) {
        f16x8 k00 = *(const f16x8*)(kh0 + kk * 32);
        f16x8 k10 = *(const f16x8*)(kh1 + kk * 32);
        f16x8 k01 = *(const f16x8*)(kh0 + kk * 32 + 32);
        f16x8 k11 = *(const f16x8*)(kh1 + kk * 32 + 32);
        a00 = __builtin_amdgcn_mfma_f32_16x16x32_f16(k00, qa[kk], a00, 0, 0, 0);
        a10 = __builtin_amdgcn_mfma_f32_16x16x32_f16(k10, qa[kk], a10, 0, 0, 0);
        a01 = __builtin_amdgcn_mfma_f32_16x16x32_f16(k01, qa[kk+1], a01, 0, 0, 0);
        a11 = __builtin_amdgcn_mfma_f32_16x16x32_f16(k11, qa[kk+1], a11, 0, 0, 0);
      }
    }
    f32x4 s0v, s1v;
#pragma unroll
    for (int r = 0; r < 4; ++r) { s0v[r] = a00[r] + a01[r]; s1v[r] = a10[r] + a11[r]; }

    // ---- step 2: softmax; P pre-scaled to exp(s - m_new); sP + sAl ----
    const unsigned mb = msk_cur;
    float se0[4], se1[4];
#pragma unroll
    for (int r = 0; r < 4; ++r) {
      se0[r] = ((mb >> (quad * 4 + r)) & 1u)      ? s0v[r] : -1e30f;
      se1[r] = ((mb >> (16 + quad * 4 + r)) & 1u) ? s1v[r] : -1e30f;
    }
    float rmax = fmaxf(fmaxf(fmaxf(se0[0], se0[1]), fmaxf(se0[2], se0[3])),
                       fmaxf(fmaxf(se1[0], se1[1]), fmaxf(se1[2], se1[3])));
    rmax = fmaxf(rmax, __shfl_xor(rmax, 16));
    rmax = fmaxf(rmax, __shfl_xor(rmax, 32));

    float m_new = fmaxf(m_ln, rmax);
    float al_ln = __expf(m_ln - m_new);

    ushort_t pb0[4], pb1[4];
    float rsum = 0.f;
#pragma unroll
    for (int r = 0; r < 4; ++r) {
      float p0 = ((mb >> (quad * 4 + r)) & 1u)      ? __expf(se0[r] - m_new) : 0.f;
      float p1 = ((mb >> (16 + quad * 4 + r)) & 1u) ? __expf(se1[r] - m_new) : 0.f;
      pb0[r] = f2h(p0); pb1[r] = f2h(p1);
      rsum += h2f(pb0[r]) + h2f(pb1[r]);
    }
    {  // producer strip write (r12 pattern): rows wave*16+l16
      uint2 w0, w1;
      w0.x = (unsigned)pb0[0] | ((unsigned)pb0[1] << 16);
      w0.y = (unsigned)pb0[2] | ((unsigned)pb0[3] << 16);
      w1.x = (unsigned)pb1[0] | ((unsigned)pb1[1] << 16);
      w1.y = (unsigned)pb1[2] | ((unsigned)pb1[3] << 16);
      *(uint2*)(&sP[wave * 16 + l16][quad * 4]) = w0;
      *(uint2*)(&sP[wave * 16 + l16][16 + quad * 4]) = w1;
    }
    if (quad == 0) sAl[wave * 16 + l16] = al_ln;
    rsum += __shfl_xor(rsum, 16);
    rsum += __shfl_xor(rsum, 32);
    l_ln = al_ln * l_ln + rsum;
    m_ln = m_new;

    // ---- step 4: counted drain + barrier (publish sP/sAl; K(i+1) visible) ----
    asm volatile("s_waitcnt vmcnt(5)" ::: "memory");   // retire K(i+1); keep V(i)+mask
    asm volatile("s_waitcnt lgkmcnt(0)" ::: "memory"); // sP/sAl writes visible
    __builtin_amdgcn_s_barrier();
    asm volatile("" ::: "memory");

    // ---- step 5: K(i+2) DMA into sK[buf] (all waves past QK(i)) ----
    if (i + 2 < NTt) issue_k(sbeg + (i + 2) * TS, buf);

    // ---- step 6: oacc rescale with per-row alphas (broadcast reads) ----
#pragma unroll
    for (int qb = 0; qb < 8; ++qb) {
      f32x4 alr = *(const f32x4*)(&sAl[qb * 16 + quad * 4]);
#pragma unroll
      for (int dt = 0; dt < 4; ++dt)
#pragma unroll
        for (int r = 0; r < 4; ++r) oacc[qb * 4 + dt][r] *= alr[r];
    }

    // ---- step 7: PV(i): per q-block one A-frag, reused over 4 d-tiles ----
#pragma unroll
    for (int qb = 0; qb < 8; ++qb) {
      f16x8 pa = *(const f16x8*)(&sP[qb * 16 + l16][quad * 8]);
#pragma unroll
      for (int dt = 0; dt < 4; ++dt) {
        oacc[qb * 4 + dt] = __builtin_amdgcn_mfma_f32_16x16x32_f16(
            pa, vb[dt], oacc[qb * 4 + dt], 0, 0, 0);
      }
    }

    msk_cur = msk_nxt;
  }

  // ---- epilogue ----
  const size_t rbase = (size_t)(b * SPLIT + sh) * NQz + q0;
#pragma unroll
  for (int qb = 0; qb < 8; ++qb) {
#pragma unroll
    for (int dt = 0; dt < 4; ++dt) {
#pragma unroll
      for (int r = 0; r < 4; ++r) {
        Opart[(rbase + qb * 16 + quad * 4 + r) * Dz + wave * 64 + dt * 16 + l16] =
            f2h(oacc[qb * 4 + dt][r]);
      }
    }
  }
  if (quad == 0) {
    Mpart[rbase + wave * 16 + l16] = m_ln;
    Lpart[rbase + wave * 16 + l16] = l_ln;
  }
}

// ---------------- combine the SPLIT S-parts (fp16 Opart) ----------------
template <int SPLIT>
__global__ __launch_bounds__(256)
void combine(const ushort_t* __restrict__ Opart, const float* __restrict__ Mpart,
             const float* __restrict__ Lpart, float* __restrict__ Out) {
  int gid = blockIdx.x * 256 + threadIdx.x;
  int row = gid >> 7;
  int b   = row >> 10;
  int q   = row & 1023;
  int c   = (gid & 127) * 4;
  float mv[SPLIT], lv[SPLIT];
  float m = -1e30f;
#pragma unroll
  for (int p = 0; p < SPLIT; ++p) {
    size_t ip = (size_t)(b * SPLIT + p) * NQz + q;
    mv[p] = Mpart[ip];
    lv[p] = Lpart[ip];
    m = fmaxf(m, mv[p]);
  }
  float w[SPLIT], denom = 0.f;
#pragma unroll
  for (int p = 0; p < SPLIT; ++p) {
    w[p] = __expf(mv[p] - m);
    denom += w[p] * lv[p];
  }
  float inv = 1.0f / denom;
  float4 o = {0.f, 0.f, 0.f, 0.f};
#pragma unroll
  for (int p = 0; p < SPLIT; ++p) {
    size_t ip = (size_t)(b * SPLIT + p) * NQz + q;
    const ushort_t* op = Opart + ip * Dz + c;
    uint2 raw = *(const uint2*)op;
    o.x += w[p] * h2f((ushort_t)(raw.x & 0xffff));
    o.y += w[p] * h2f((ushort_t)(raw.x >> 16));
    o.z += w[p] * h2f((ushort_t)(raw.y & 0xffff));
    o.w += w[p] * h2f((ushort_t)(raw.y >> 16));
  }
  o.x *= inv; o.y *= inv; o.z *= inv; o.w *= inv;
  *(float4*)(Out + ((size_t)b * NQz + q) * Dz + c) = o;
}

extern "C" void kernel_launch(void* const* d_in, const int* in_sizes, int n_in,
                              void* d_out, int out_size, void* d_ws, size_t ws_size,
                              hipStream_t stream) {
  const float* Q = (const float*)d_in[0];
  const float* K = (const float*)d_in[1];
  const float* V = (const float*)d_in[2];
  const int*   M = (const int*)d_in[3];
  float* O = (float*)d_out;

  const size_t NKV   = (size_t)Bz * Sz * Dz;        // f16 elems per tensor
  const size_t maskW = (size_t)Bz * NQz * (Sz / 32);

  // Split-independent layout: Kf | Vt | Mp | Opart(fp16) | Mpart | Lpart
  ushort_t* Kf = (ushort_t*)d_ws;
  ushort_t* Vt = Kf + NKV;
  unsigned* Mp = (unsigned*)(Vt + NKV);
  ushort_t* Opart = (ushort_t*)(Mp + maskW);

  auto need_bytes = [&](int S) -> size_t {
    return NKV * 2 * 2 + maskW * 4
         + (size_t)Bz * S * NQz * Dz * 2       // Opart fp16
         + (size_t)Bz * S * NQz * 4 * 2;       // Mpart + Lpart
  };

  prep<<<dim3(10240), dim3(256), 0, stream>>>(K, V, M, Kf, Vt, Mp);

  if (ws_size >= need_bytes(4)) {
    constexpr int S = 4;
    float* Mpart = (float*)(Opart + (size_t)Bz * S * NQz * Dz);
    float* Lpart = Mpart + (size_t)Bz * S * NQz;
    attn_flash<S><<<dim3(8 * (NQz / QTT) * S), dim3(512), 0, stream>>>(
        Q, Mp, Kf, Vt, Opart, Mpart, Lpart);
    combine<S><<<dim3(4096), dim3(256), 0, stream>>>(Opart, Mpart, Lpart, O);
  } else {
    constexpr int S = 2;
    float* Mpart = (float*)(Opart + (size_t)Bz * S * NQz * Dz);
    float* Lpart = Mpart + (size_t)Bz * S * NQz;
    attn_flash<S><<<dim3(8 * (NQz / QTT) * S), dim3(512), 0, stream>>>(
        Q, Mp, Kf, Vt, Opart, Mpart, Lpart);
    combine<S><<<dim3(4096), dim3(256), 0, stream>>>(Opart, Mpart, Lpart, O);
  }
}